// Round 2
// baseline (201.074 us; speedup 1.0000x reference)
//
#include <hip/hip_runtime.h>
#include <cstdint>

#define N 8192
#define BLK 512         // threads per block (8 waves)
#define NBLK 1024       // 4 blocks/CU x 256 CU -> exactly 32 waves/CU resident
#define NPAIRS 4096     // row-pairs: pair p = rows {p, 8190-p}, combined length N

// Partial of sum_e c2[O+e] * x[i+1+e] over this block's threads.
// c2 accessed as aligned float4 (prolog/tail per row); x read from LDS in
// deinterleaved layout xs[idx&3][idx>>2] -> lane-stride-1 -> conflict-free.
__device__ __forceinline__ float row_partial(const float* __restrict__ c2,
                                             const float (&xs)[4][2048],
                                             int O, int L, int i) {
    const int t = threadIdx.x;
    const float* cp = c2 + O;
    const int xb0 = i + 1;
    float s = 0.0f;

    int pro = (4 - (O & 3)) & 3;          // scalars until c2 is 16B-aligned
    if (pro > L) pro = L;
    if (t < pro) {
        const int xi = xb0 + t;
        s += cp[t] * xs[xi & 3][xi >> 2];
    }

    const int R = L - pro;
    const int V = R >> 2;
    const int tail = R & 3;
    const float4* __restrict__ cv = (const float4*)(cp + pro);
    const int xb = xb0 + pro;

    for (int v = t; v < V; v += BLK) {
        const float4 c = cv[v];
        const int xi = xb + (v << 2);
        const float x0 = xs[xi & 3][xi >> 2];
        const float x1 = xs[(xi + 1) & 3][(xi + 1) >> 2];
        const float x2 = xs[(xi + 2) & 3][(xi + 2) >> 2];
        const float x3 = xs[(xi + 3) & 3][(xi + 3) >> 2];
        s += c.x * x0 + c.y * x1 + c.z * x2 + c.w * x3;
    }
    if (t < tail) {
        const int e = (V << 2) + t;
        const int xi = xb + e;
        s += cp[pro + e] * xs[xi & 3][xi >> 2];
    }
    return s;
}

__global__ __launch_bounds__(BLK) void ham_main(const float* __restrict__ x,
                                                const float* __restrict__ coeffs,
                                                float* __restrict__ ws) {
    __shared__ float xs[4][2048];         // 32 KB: x deinterleaved, x[i] -> xs[i&3][i>>2]
    const int t = threadIdx.x;
    const int b = blockIdx.x;
    const float* __restrict__ c1 = coeffs;
    const float* __restrict__ c2 = coeffs + N;

    // Stage x -> LDS (coalesced float4 reads; each of the 4 LDS writes is lane-stride-1)
    {
        const float4* __restrict__ x4 = (const float4*)x;
        for (int k = t; k < 2048; k += BLK) {
            const float4 v = x4[k];
            xs[0][k] = v.x; xs[1][k] = v.y; xs[2][k] = v.z; xs[3][k] = v.w;
        }
    }
    __syncthreads();

    float acc = 0.0f;

    #pragma unroll
    for (int pp = 0; pp < 4; ++pp) {
        const int p = b + pp * NBLK;      // row-pair index
        const int i1 = p;                 // length N-1-i1
        const int O1 = (i1 * (2 * N - i1 - 1)) >> 1;   // fits in int (max ~33.5M)
        acc += xs[i1 & 3][i1 >> 2] * row_partial(c2, xs, O1, N - 1 - i1, i1);

        const int i2 = N - 2 - p;         // length p+1; skip self-paired middle row
        if (i2 > i1) {
            const int O2 = (i2 * (2 * N - i2 - 1)) >> 1;
            acc += xs[i2 & 3][i2 >> 2] * row_partial(c2, xs, O2, N - 1 - i2, i2);
        }
    }

    // Degree-1 terms: 8 per block
    if (t < 8) {
        const int g = (b << 3) + t;
        acc += c1[g] * xs[g & 3][g >> 2];
    }

    // Block reduction: 64-wide shuffle then cross-wave LDS
    #pragma unroll
    for (int o = 32; o > 0; o >>= 1) acc += __shfl_down(acc, o, 64);
    __shared__ float smem[BLK / 64];
    const int wave = t >> 6;
    const int lane = t & 63;
    if (lane == 0) smem[wave] = acc;
    __syncthreads();
    if (t == 0) {
        float v = 0.0f;
        #pragma unroll
        for (int w = 0; w < BLK / 64; ++w) v += smem[w];
        ws[b] = v;                        // unconditional write; never read-before-write
    }
}

__global__ __launch_bounds__(256) void ham_reduce(const float* __restrict__ ws,
                                                  float* __restrict__ out) {
    const int t = threadIdx.x;
    const float4* __restrict__ w4 = (const float4*)ws;   // 1024 floats = 256 float4
    const float4 v4 = w4[t];
    float v = v4.x + v4.y + v4.z + v4.w;
    #pragma unroll
    for (int o = 32; o > 0; o >>= 1) v += __shfl_down(v, o, 64);
    __shared__ float smem[4];
    const int wave = t >> 6;
    const int lane = t & 63;
    if (lane == 0) smem[wave] = v;
    __syncthreads();
    if (t == 0) out[0] = smem[0] + smem[1] + smem[2] + smem[3];
}

extern "C" void kernel_launch(void* const* d_in, const int* in_sizes, int n_in,
                              void* d_out, int out_size, void* d_ws, size_t ws_size,
                              hipStream_t stream) {
    const float* x      = (const float*)d_in[0];
    const float* coeffs = (const float*)d_in[1];
    float* out = (float*)d_out;
    float* ws  = (float*)d_ws;            // uses NBLK*4 = 4 KB

    ham_main<<<NBLK, BLK, 0, stream>>>(x, coeffs, ws);
    ham_reduce<<<1, 256, 0, stream>>>(ws, out);
}